// Round 11
// baseline (5708.203 us; speedup 1.0000x reference)
//
#include <hip/hip_runtime.h>

// LSTM_50208167690847 v11: 2-layer BiLSTM (B=256,T=512,IN=64,H=256) + FC.
// v10 -> v11: two-group interleave. Each block runs TWO independent
// batch-group recurrences (same direction -> same LDS weights) as
// alternating half-steps. Poll samples for group X are pre-issued at the
// end of X's half; group Y's compute (~a full half-step) fills the
// issue->check gap, so the sample is fresh and the fabric RTT is hidden.
// Per half-step wait ∈ {0, RTT} vs v10's {RTT, 2RTT} -- strictly >= v10.
// Exchange protocol unchanged (proven): tagged u64 {step,2xf16} data-poll,
// relaxed AGENT-scope atomics, parity double-buffer, skip-own-words,
// 0xFF tag poison per launch. 128 blocks per scan.

#define T_ 512
#define IN_ 64
#define H_ 256

typedef __attribute__((ext_vector_type(8))) _Float16 f16x8;
typedef __attribute__((ext_vector_type(4))) _Float16 f16x4;
typedef __attribute__((ext_vector_type(4))) float f32x4;
typedef unsigned long long u64;
typedef unsigned int u32;

__device__ __forceinline__ float sigm(float x){ return 1.f/(1.f+__expf(-x)); }
__device__ __forceinline__ float tanh_(float x){ return 1.f - 2.f/(__expf(2.f*x)+1.f); }

// pack weights into per-(dir,q) MFMA-B fragment order:
// flat = ((((dir*NQ+q)*4 + gt)*NSUB + sub)*KT + kt)*512 + lane*8 + e
// gate col g = gt*256 + q*QW + sub*16 + (lane&15); k = kt*32 + (lane>>4)*8 + e
__global__ void pack_w(const float* __restrict__ ih, const float* __restrict__ hh,
                       _Float16* __restrict__ dst, int KX, int KH, int KT,
                       int QW, int NSUB, int NQ, int total) {
    int idx = blockIdx.x * 256 + threadIdx.x;
    if (idx >= total) return;
    int e = idx & 7, lane = (idx >> 3) & 63;
    int u = idx >> 9;
    int kt = u % KT; u /= KT;
    int sub = u % NSUB; u /= NSUB;
    int gt = u & 3; u >>= 2;
    int q = u % NQ; int dir = u / NQ;
    int g = gt * 256 + q * QW + sub * 16 + (lane & 15);
    int k = kt * 32 + (lane >> 4) * 8 + e;
    float v = (k < KX) ? ih[(size_t)(dir * 1024 + g) * KX + k]
                       : hh[(size_t)(dir * 1024 + g) * KH + (k - KX)];
    dst[idx] = (_Float16)v;
}

// Block map: pair p = bid % NPAIR, q = bid / NPAIR. Pair handles groups
// grp0 = (dir*16 + 2*bgp) and grp0+1 (same dir -> shared weight slice).
template <int KXT, int KHT, int QW, bool IS_L0>
__global__ __launch_bounds__(256)
void lstm_scan(const float* __restrict__ x, const _Float16* __restrict__ xin,
               const _Float16* __restrict__ wpack, const float* __restrict__ bias,
               u64* __restrict__ hbuf,
               _Float16* __restrict__ out0, float* __restrict__ hlast) {
    constexpr int MROWS = 16;
    constexpr int KT = KXT + KHT, KX = KXT * 32;
    constexpr int NTHR = 256;
    constexpr int NSUB = QW / 16, NQ = 256 / QW;
    constexpr int NPAIR = IS_L0 ? 16 : 8;
    constexpr int WBE = 4 * NSUB * KT * 512;    // weight slice elems
    constexpr int KP = KX + 8;                  // a_lds f16 row stride
    constexpr int HPW = 132;                    // h_lds u32 row stride
    constexpr int GP = QW + 1;
    constexpr int NWORD = MROWS * 128;          // u64 words per group-buffer (2048)
    constexpr int NW = NWORD / NTHR;            // words per thread (8)
    constexpr int OWNW = QW / 2;                // own u64-col width

    extern __shared__ char smem[];
    _Float16* w_lds = (_Float16*)smem;
    u32*      h32   = (u32*)(smem + (size_t)WBE * 2);
    _Float16* a_all = (_Float16*)(smem + (size_t)WBE * 2 + 2u * MROWS * HPW * 4);
    float*    g_all = (float*)(smem + (size_t)WBE * 2 + 2u * MROWS * HPW * 4
                               + 2u * MROWS * KP * 2);

    const int tid = threadIdx.x, lane = tid & 63, wave = tid >> 6;
    const int p = blockIdx.x % NPAIR, q = blockIdx.x / NPAIR;
    const int dir = IS_L0 ? (p >> 3) : 0;
    const int bgp = IS_L0 ? (p & 7) : p;
    const int grp0 = dir * 16 + bgp * 2;        // L1: dir=0 -> 2p
    const int b0rbase = bgp * 32;
    const int gt = wave;                        // wave == gate

    // stage weight slice into LDS (once; shared by both groups)
    {
        const f16x8* src = (const f16x8*)(wpack + (size_t)(dir * NQ + q) * WBE);
        f16x8* dst = (f16x8*)w_lds;
        for (int i = tid; i < WBE / 8; i += NTHR) dst[i] = src[i];
    }

    // elementwise mapping (same for both groups)
    const int erow = tid >> 4, ecp = tid & 15;
    float b_[4][NSUB];
#pragma unroll
    for (int g4 = 0; g4 < 4; ++g4)
#pragma unroll
        for (int j = 0; j < NSUB; ++j)
            b_[g4][j] = bias[dir * 1024 + g4 * 256 + q * QW + ecp * NSUB + j];
    float c_reg[2][NSUB];
#pragma unroll
    for (int g01 = 0; g01 < 2; ++g01)
#pragma unroll
        for (int j = 0; j < NSUB; ++j) c_reg[g01][j] = 0.f;

    // gather role; own words written locally
    const int colp = tid & 127;
    const bool skip = (colp >= q * OWNW) && (colp < q * OWNW + OWNW);

    // x staging: t0 into a_lds, t1 prefetched to regs (both groups)
    float4 xv[2];           // L0
    f16x8 xp[2][4];         // L1
    {
        int t0 = dir ? (T_ - 1) : 0;
        int t1 = dir ? (T_ - 2) : 1;
#pragma unroll
        for (int g01 = 0; g01 < 2; ++g01) {
            _Float16* a_g = a_all + (size_t)g01 * MROWS * KP;
            const int b0r = b0rbase + g01 * 16;
            if constexpr (IS_L0) {
                const int xrow = tid >> 4, c4 = (tid & 15) * 4;
                float4 v0 = *(const float4*)&x[((size_t)(b0r + xrow) * T_ + t0) * IN_ + c4];
                f16x4 h4; h4[0]=(_Float16)v0.x; h4[1]=(_Float16)v0.y; h4[2]=(_Float16)v0.z; h4[3]=(_Float16)v0.w;
                *(f16x4*)&a_g[(size_t)xrow * KP + c4] = h4;
                xv[g01] = *(const float4*)&x[((size_t)(b0r + xrow) * T_ + t1) * IN_ + c4];
            } else {
#pragma unroll
                for (int j = 0; j < 4; ++j) {
                    int ch = j * NTHR + tid;
                    int r2 = ch >> 6, c8 = (ch & 63) * 8;
                    f16x8 v = *(const f16x8*)&xin[((size_t)(b0r + r2) * T_ + t0) * 512 + c8];
                    *(f16x8*)&a_g[(size_t)r2 * KP + c8] = v;
                }
#pragma unroll
                for (int j = 0; j < 4; ++j) {
                    int ch = j * NTHR + tid;
                    int r2 = ch >> 6, c8 = (ch & 63) * 8;
                    xp[g01][j] = *(const f16x8*)&xin[((size_t)(b0r + r2) * T_ + t1) * 512 + c8];
                }
            }
        }
    }
    __syncthreads();

    const int arow = lane & 15;
    const int kc8 = (lane >> 4) * 8;

    u64 ga[2][NW];   // pre-issued poll samples per group (loop-carried)

    for (int s = 0; s < T_; ++s) {
        const int t = dir ? (T_ - 1 - s) : s;

#pragma unroll
        for (int g01 = 0; g01 < 2; ++g01) {
            _Float16* a_g = a_all + (size_t)g01 * MROWS * KP;
            u32* h32g = h32 + (size_t)g01 * MROWS * HPW;
            float* g_g = g_all + (size_t)g01 * 4 * MROWS * GP;
            const int grp = grp0 + g01;
            const int b0r = b0rbase + g01 * 16;

            // ---- phase A: x-part MFMAs ----
            f32x4 acc[NSUB][2];
#pragma unroll
            for (int sub = 0; sub < NSUB; ++sub) {
                f32x4 z = {0.f, 0.f, 0.f, 0.f};
                acc[sub][0] = z; acc[sub][1] = z;
            }
#pragma unroll
            for (int kt = 0; kt < KXT; ++kt) {
                f16x8 a = *(const f16x8*)&a_g[(size_t)arow * KP + kt * 32 + kc8];
#pragma unroll
                for (int sub = 0; sub < NSUB; ++sub) {
                    f16x8 b = *(const f16x8*)&w_lds[(((size_t)(gt * NSUB + sub) * KT + kt) * 64 + lane) * 8];
                    acc[sub][kt & 1] = __builtin_amdgcn_mfma_f32_16x16x32_f16(a, b, acc[sub][kt & 1], 0, 0, 0);
                }
            }

            // ---- phase B: check pre-issued samples; retry stale ----
            if (s > 0 && !skip) {
                const u32 want = (u32)(s - 1);
                u64* bw = hbuf + ((size_t)grp * 2 + ((s - 1) & 1)) * NWORD;
                u32 pend = (1u << NW) - 1u;
                for (;;) {
#pragma unroll
                    for (int k = 0; k < NW; ++k) {
                        if ((pend & (1u << k)) && (u32)(ga[g01][k] >> 32) == want) {
                            int w = k * NTHR + tid;
                            h32g[(size_t)(w >> 7) * HPW + (w & 127)] = (u32)ga[g01][k];
                            pend &= ~(1u << k);
                        }
                    }
                    if (!pend) break;
#pragma unroll
                    for (int k = 0; k < NW; ++k)
                        if (pend & (1u << k))
                            ga[g01][k] = __hip_atomic_load(&bw[k * NTHR + tid], __ATOMIC_RELAXED,
                                                           __HIP_MEMORY_SCOPE_AGENT);
                }
            }
            __syncthreads();   // h32g ready; phase-A a_g reads done

            // stage x(s+1) into a_g (from prefetch regs)
            if constexpr (IS_L0) {
                const int xrow = tid >> 4, c4 = (tid & 15) * 4;
                f16x4 h4; h4[0]=(_Float16)xv[g01].x; h4[1]=(_Float16)xv[g01].y;
                h4[2]=(_Float16)xv[g01].z; h4[3]=(_Float16)xv[g01].w;
                *(f16x4*)&a_g[(size_t)xrow * KP + c4] = h4;
            } else {
#pragma unroll
                for (int j = 0; j < 4; ++j) {
                    int ch = j * NTHR + tid;
                    int r2 = ch >> 6, c8 = (ch & 63) * 8;
                    *(f16x8*)&a_g[(size_t)r2 * KP + c8] = xp[g01][j];
                }
            }

            // ---- phase C: h-part MFMAs ----
            if (s > 0) {
#pragma unroll
                for (int kt = 0; kt < KHT; ++kt) {
                    f16x8 a = *(const f16x8*)&h32g[(size_t)arow * HPW + kt * 16 + (lane >> 4) * 4];
#pragma unroll
                    for (int sub = 0; sub < NSUB; ++sub) {
                        f16x8 b = *(const f16x8*)&w_lds[(((size_t)(gt * NSUB + sub) * KT + KXT + kt) * 64 + lane) * 8];
                        acc[sub][kt & 1] = __builtin_amdgcn_mfma_f32_16x16x32_f16(a, b, acc[sub][kt & 1], 0, 0, 0);
                    }
                }
            }
            {
                const int crow = (lane >> 4) * 4, ccol = lane & 15;
#pragma unroll
                for (int sub = 0; sub < NSUB; ++sub) {
                    f32x4 av = acc[sub][0] + acc[sub][1];
#pragma unroll
                    for (int qq = 0; qq < 4; ++qq)
                        g_g[(size_t)(gt * MROWS + crow + qq) * GP + sub * 16 + ccol] = av[qq];
                }
            }
            __syncthreads();   // gates ready; a_g staged for next step

            // ---- phase D: elementwise; publish; own-word; pre-issue ----
            float hval[NSUB];
#pragma unroll
            for (int j = 0; j < NSUB; ++j) {
                float gI = g_g[(size_t)(0 * MROWS + erow) * GP + ecp * NSUB + j] + b_[0][j];
                float gF = g_g[(size_t)(1 * MROWS + erow) * GP + ecp * NSUB + j] + b_[1][j];
                float gG = g_g[(size_t)(2 * MROWS + erow) * GP + ecp * NSUB + j] + b_[2][j];
                float gO = g_g[(size_t)(3 * MROWS + erow) * GP + ecp * NSUB + j] + b_[3][j];
                float i_ = sigm(gI), f_ = sigm(gF), g2 = tanh_(gG), o_ = sigm(gO);
                c_reg[g01][j] = f_ * c_reg[g01][j] + i_ * g2;
                hval[j] = o_ * tanh_(c_reg[g01][j]);
            }
            u64* bw2 = hbuf + ((size_t)grp * 2 + (s & 1)) * NWORD;
            if constexpr (NSUB == 2) {
                union { _Float16 h[2]; u32 u; } pk;
                pk.h[0] = (_Float16)hval[0]; pk.h[1] = (_Float16)hval[1];
                if (s + 1 < T_) {
                    u64 word = (u64)pk.u | ((u64)(u32)s << 32);
                    __hip_atomic_store(&bw2[erow * 128 + q * 16 + ecp], word,
                                       __ATOMIC_RELAXED, __HIP_MEMORY_SCOPE_AGENT);
                    h32g[(size_t)erow * HPW + q * 16 + ecp] = pk.u;
                }
                if constexpr (IS_L0) {
                    *(u32*)&out0[((size_t)(b0r + erow) * T_ + t) * 512 + dir * 256 + q * QW + ecp * 2] = pk.u;
                }
            } else {
                union { _Float16 h; unsigned short u; } hb; hb.h = (_Float16)hval[0];
                u32 ov = (u32)__shfl_xor((int)hb.u, 1);
                u32 lo = (u32)hb.u | ((ov & 0xFFFFu) << 16);
                if (!(lane & 1) && s + 1 < T_) {
                    u64 word = (u64)lo | ((u64)(u32)s << 32);
                    __hip_atomic_store(&bw2[erow * 128 + ((q * 16 + ecp) >> 1)], word,
                                       __ATOMIC_RELAXED, __HIP_MEMORY_SCOPE_AGENT);
                    h32g[(size_t)erow * HPW + q * (QW / 2) + (ecp >> 1)] = lo;
                }
            }
            if constexpr (!IS_L0) {
                if (s == T_ - 1)
                    hlast[(size_t)(b0r + erow) * 256 + q * QW + ecp] = hval[0];
            }
            // prefetch x(s+2)
            {
                int sn2 = (s + 2 < T_) ? s + 2 : T_ - 1;
                int t2 = dir ? (T_ - 1 - sn2) : sn2;
                if constexpr (IS_L0) {
                    const int xrow = tid >> 4, c4 = (tid & 15) * 4;
                    xv[g01] = *(const float4*)&x[((size_t)(b0r + xrow) * T_ + t2) * IN_ + c4];
                } else {
#pragma unroll
                    for (int j = 0; j < 4; ++j) {
                        int ch = j * NTHR + tid;
                        int r2 = ch >> 6, c8 = (ch & 63) * 8;
                        xp[g01][j] = *(const f16x8*)&xin[((size_t)(b0r + r2) * T_ + t2) * 512 + c8];
                    }
                }
            }
            // pre-issue next poll samples for this group (freshest = last)
            if (s + 1 < T_ && !skip) {
#pragma unroll
                for (int k = 0; k < NW; ++k)
                    ga[g01][k] = __hip_atomic_load(&bw2[k * NTHR + tid], __ATOMIC_RELAXED,
                                                   __HIP_MEMORY_SCOPE_AGENT);
            }
        }  // g01 halves
    }
}

// layer1 backward single step (t=T-1, zero state) + FC over [h1f | hb]
__global__ __launch_bounds__(256)
void tail_kernel(const _Float16* __restrict__ out0, const float* __restrict__ Wih1,
                 const float* __restrict__ b1, const float* __restrict__ fcw,
                 const float* __restrict__ fcb, const float* __restrict__ h1f,
                 float* __restrict__ out) {
    const int b = blockIdx.x, tid = threadIdx.x;
    __shared__ float xs[512];
    __shared__ float red[256];
    for (int i = tid; i < 512; i += 256)
        xs[i] = (float)out0[((size_t)b * T_ + (T_ - 1)) * 512 + i];
    __syncthreads();
    const float* Wb = Wih1 + (size_t)1024 * 512;  // dir 1
    const float* wI = Wb + (size_t)tid * 512;
    const float* wG = Wb + (size_t)(512 + tid) * 512;
    const float* wO = Wb + (size_t)(768 + tid) * 512;
    float aI = 0.f, aG = 0.f, aO = 0.f;
    for (int k = 0; k < 512; k += 4) {
        float4 xv = *(const float4*)&xs[k];
        float4 w0 = *(const float4*)&wI[k];
        float4 w1 = *(const float4*)&wG[k];
        float4 w2 = *(const float4*)&wO[k];
        aI += xv.x * w0.x + xv.y * w0.y + xv.z * w0.z + xv.w * w0.w;
        aG += xv.x * w1.x + xv.y * w1.y + xv.z * w1.z + xv.w * w1.w;
        aO += xv.x * w2.x + xv.y * w2.y + xv.z * w2.z + xv.w * w2.w;
    }
    float i_ = sigm(aI + b1[1024 + tid]);
    float g_ = tanh_(aG + b1[1024 + 512 + tid]);
    float o_ = sigm(aO + b1[1024 + 768 + tid]);
    float c = i_ * g_;  // c0 = 0
    float hb = o_ * tanh_(c);
    float part = h1f[b * 256 + tid] * fcw[tid] + hb * fcw[256 + tid];
    red[tid] = part;
    __syncthreads();
    for (int sx = 128; sx > 0; sx >>= 1) {
        if (tid < sx) red[tid] += red[tid + sx];
        __syncthreads();
    }
    if (tid == 0) out[b] = red[0] + fcb[0];
}

extern "C" void kernel_launch(void* const* d_in, const int* in_sizes, int n_in,
                              void* d_out, int out_size, void* d_ws, size_t ws_size,
                              hipStream_t stream) {
    const float* x    = (const float*)d_in[0];
    const float* Wih0 = (const float*)d_in[1];
    const float* Whh0 = (const float*)d_in[2];
    const float* b0   = (const float*)d_in[3];
    const float* Wih1 = (const float*)d_in[4];
    const float* Whh1 = (const float*)d_in[5];
    const float* b1   = (const float*)d_in[6];
    const float* fcw  = (const float*)d_in[7];
    const float* fcb  = (const float*)d_in[8];

    char* ws = (char*)d_ws;
    _Float16* W0pack = (_Float16*)(ws + 0);          // 1,310,720 B
    _Float16* W1pack = (_Float16*)(ws + 1310720);    // 1,572,864 B -> 2,883,584
    u64* hbuf0       = (u64*)(ws + 2883584);         // 1,048,576 B
    u64* hbuf1       = (u64*)(ws + 3932160);         //   524,288 B
    float* h1f       = (float*)(ws + 4456448);       //   262,144 B
    _Float16* out0   = (_Float16*)(ws + 4718592);    // 134,217,728 B -> ~138.9 MB

    // poison tag buffers (0xFFFFFFFF != any step); replay-safe
    hipMemsetAsync(ws + 2883584, 0xFF, 1572864, stream);

    // L0: QW=32, NSUB=2, NQ=8, KT=10, dirs=2 -> 655360 elems
    hipLaunchKernelGGL(pack_w, dim3(2560), dim3(256), 0, stream,
                       Wih0, Whh0, W0pack, 64, 256, 10, 32, 2, 8, 655360);
    // L1: QW=16, NSUB=1, NQ=16, KT=24, dirs=1 -> 786432 elems
    hipLaunchKernelGGL(pack_w, dim3(3072), dim3(256), 0, stream,
                       Wih1, Whh1, W1pack, 512, 256, 24, 16, 1, 16, 786432);

    // L0 LDS: 81920(w) + 16896(2xh) + 4608(2xa) + 16896(2xg) = 120,320
    hipFuncSetAttribute((const void*)(lstm_scan<2, 8, 32, true>),
                        hipFuncAttributeMaxDynamicSharedMemorySize, 120320);
    // L1 LDS: 98304(w) + 16896(2xh) + 33280(2xa) + 8704(2xg) = 157,184
    hipFuncSetAttribute((const void*)(lstm_scan<16, 8, 16, false>),
                        hipFuncAttributeMaxDynamicSharedMemorySize, 157184);

    // L0: 16 pairs (2 dir x 8 bg-pairs) x 8 col-blocks = 128 blocks
    hipLaunchKernelGGL((lstm_scan<2, 8, 32, true>), dim3(128), dim3(256), 120320, stream,
                       x, (const _Float16*)nullptr, W0pack, b0, hbuf0,
                       out0, (float*)nullptr);
    // L1: 8 pairs x 16 col-blocks = 128 blocks, K=768 folded
    hipLaunchKernelGGL((lstm_scan<16, 8, 16, false>), dim3(128), dim3(256), 157184, stream,
                       (const float*)nullptr, (const _Float16*)out0, W1pack, b1, hbuf1,
                       (_Float16*)nullptr, h1f);
    hipLaunchKernelGGL(tail_kernel, dim3(256), dim3(256), 0, stream,
                       out0, Wih1, b1, fcw, fcb, h1f, (float*)d_out);
}

// Round 12
// 2476.816 us; speedup vs baseline: 2.3047x; 2.3047x over previous
//
#include <hip/hip_runtime.h>

// LSTM_50208167690847 v12: 2-layer BiLSTM (B=256,T=512,IN=64,H=256) + FC.
// v10 -> v12 (v11 interleave reverted - barrier-coupled waits serialize):
//  L0 rebuilt at QW=64 / NQ=4 (was 32/8): x-part weights (KXT=2, 32KB) live
//  in VGPRs (loaded once), LDS holds only h-part weights (128KB) -> the
//  wider column split fits. Gather volume 3.67 -> 1.54 MB/step (2.4x cut),
//  poll fan-in 7 -> 3 remote publishers. Protocol byte-identical to v10:
//  tagged u64 {step,2xf16} data-poll, relaxed AGENT atomics, phase-B
//  sampling, skip-own-words, parity double-buffer, 0xFF poison.
//  L1 kept exactly v10 (isolates the L0 experiment).

#define T_ 512
#define IN_ 64
#define H_ 256

typedef __attribute__((ext_vector_type(8))) _Float16 f16x8;
typedef __attribute__((ext_vector_type(4))) _Float16 f16x4;
typedef __attribute__((ext_vector_type(4))) float f32x4;
typedef unsigned long long u64;
typedef unsigned int u32;

__device__ __forceinline__ float sigm(float x){ return 1.f/(1.f+__expf(-x)); }
__device__ __forceinline__ float tanh_(float x){ return 1.f - 2.f/(__expf(2.f*x)+1.f); }

// pack weights into per-(dir,q) MFMA-B fragment order:
// flat = ((((dir*NQ+q)*4 + gt)*NSUB + sub)*KT + kt)*512 + lane*8 + e
// gate col g = gt*256 + q*QW + sub*16 + (lane&15); k = kt*32 + (lane>>4)*8 + e
__global__ void pack_w(const float* __restrict__ ih, const float* __restrict__ hh,
                       _Float16* __restrict__ dst, int KX, int KH, int KT,
                       int QW, int NSUB, int NQ, int total) {
    int idx = blockIdx.x * 256 + threadIdx.x;
    if (idx >= total) return;
    int e = idx & 7, lane = (idx >> 3) & 63;
    int u = idx >> 9;
    int kt = u % KT; u /= KT;
    int sub = u % NSUB; u /= NSUB;
    int gt = u & 3; u >>= 2;
    int q = u % NQ; int dir = u / NQ;
    int g = gt * 256 + q * QW + sub * 16 + (lane & 15);
    int k = kt * 32 + (lane >> 4) * 8 + e;
    float v = (k < KX) ? ih[(size_t)(dir * 1024 + g) * KX + k]
                       : hh[(size_t)(dir * 1024 + g) * KH + (k - KX)];
    dst[idx] = (_Float16)v;
}

// Block map: grp = bid % NGRP, q = bid / NGRP.
template <int KXT, int KHT, int QW, bool IS_L0>
__global__ __launch_bounds__(256)
void lstm_scan(const float* __restrict__ x, const _Float16* __restrict__ xin,
               const _Float16* __restrict__ wpack, const float* __restrict__ bias,
               u64* __restrict__ hbuf,
               _Float16* __restrict__ out0, float* __restrict__ hlast) {
    constexpr int MROWS = 16;
    constexpr int KT = KXT + KHT, KX = KXT * 32;
    constexpr int NTHR = 256;
    constexpr int NSUB = QW / 16, NQ = 256 / QW;
    constexpr int NGRP = IS_L0 ? 32 : 16;
    constexpr bool XREG = IS_L0;                // x-part weights in VGPRs
    constexpr int WBE = 4 * NSUB * KT * 512;    // packed slice elems (global)
    constexpr int KP = KX + 8;                  // a_lds f16 row stride
    constexpr int HPW = 132;                    // h_lds u32 row stride
    constexpr int GP = QW + 1;
    constexpr int NWORD = MROWS * 128;          // u64 words per group-buffer (2048)
    constexpr int NW = NWORD / NTHR;            // words per thread (8)
    constexpr int OWNW = QW / 2;                // own payload-col width

    extern __shared__ char smem[];
    _Float16* w_lds = (_Float16*)smem;          // L0: h-part only; L1: full
    constexpr int WLDS = XREG ? (4 * NSUB * KHT * 512) : WBE;
    u32*      h32   = (u32*)(smem + (size_t)WLDS * 2);
    _Float16* a_lds = (_Float16*)(smem + (size_t)WLDS * 2 + (size_t)MROWS * HPW * 4);
    float*    g_lds = (float*)(smem + (size_t)WLDS * 2 + (size_t)MROWS * HPW * 4
                               + (size_t)MROWS * KP * 2);

    const int tid = threadIdx.x, lane = tid & 63, wave = tid >> 6;
    const int grp = blockIdx.x % NGRP, q = blockIdx.x / NGRP;
    const int dir = IS_L0 ? (grp >> 4) : 0;
    const int b0r = (IS_L0 ? (grp & 15) : grp) * MROWS;
    const int gt = wave;                        // wave == gate

    const f16x8* wsrc8 = (const f16x8*)(wpack + (size_t)(dir * NQ + q) * WBE);

    // x-part weight fragments -> VGPRs (L0 only; loaded once)
    f16x8 bx[NSUB][KXT > 0 ? KXT : 1];
    if constexpr (XREG) {
#pragma unroll
        for (int sub = 0; sub < NSUB; ++sub)
#pragma unroll
            for (int kt = 0; kt < KXT; ++kt)
                bx[sub][kt] = wsrc8[(size_t)((gt * NSUB + sub) * KT + kt) * 64 + lane];
    }

    // stage weight slice into LDS (once)
    {
        f16x8* wdst = (f16x8*)w_lds;
        if constexpr (XREG) {
            // h-part only: dst chunk i = sidx*(KHT*64) + kth*64 + l
            for (int i = tid; i < WLDS / 8; i += NTHR) {
                int sidx = i >> 9;               // /(KHT*64) with KHT=8
                int rem = i & 511;
                int kth = rem >> 6, l = rem & 63;
                wdst[i] = wsrc8[(size_t)(sidx * KT + KXT + kth) * 64 + l];
            }
        } else {
            for (int i = tid; i < WLDS / 8; i += NTHR) wdst[i] = wsrc8[i];
        }
    }

    // elementwise mapping: thread -> (row erow, NSUB cols at q*QW + ecp*NSUB)
    const int erow = tid >> 4, ecp = tid & 15;
    float b_[4][NSUB], c_reg[NSUB];
#pragma unroll
    for (int g4 = 0; g4 < 4; ++g4)
#pragma unroll
        for (int j = 0; j < NSUB; ++j)
            b_[g4][j] = bias[dir * 1024 + g4 * 256 + q * QW + ecp * NSUB + j];
#pragma unroll
    for (int j = 0; j < NSUB; ++j) c_reg[j] = 0.f;

    // gather role: payload col = tid & 127; own cols written locally
    const int colp = tid & 127;
    const bool skip = (colp >= q * OWNW) && (colp < q * OWNW + OWNW);

    // x staging: t0 into a_lds, t1 prefetched to regs
    float4 xv;            // L0
    f16x8 xp[4];          // L1
    {
        int t0 = dir ? (T_ - 1) : 0;
        int t1 = dir ? (T_ - 2) : 1;
        if constexpr (IS_L0) {
            const int xrow = tid >> 4, c4 = (tid & 15) * 4;
            float4 v0 = *(const float4*)&x[((size_t)(b0r + xrow) * T_ + t0) * IN_ + c4];
            f16x4 h4; h4[0]=(_Float16)v0.x; h4[1]=(_Float16)v0.y; h4[2]=(_Float16)v0.z; h4[3]=(_Float16)v0.w;
            *(f16x4*)&a_lds[(size_t)xrow * KP + c4] = h4;
            xv = *(const float4*)&x[((size_t)(b0r + xrow) * T_ + t1) * IN_ + c4];
        } else {
#pragma unroll
            for (int j = 0; j < 4; ++j) {
                int ch = j * NTHR + tid;
                int r2 = ch >> 6, c8 = (ch & 63) * 8;
                f16x8 v = *(const f16x8*)&xin[((size_t)(b0r + r2) * T_ + t0) * 512 + c8];
                *(f16x8*)&a_lds[(size_t)r2 * KP + c8] = v;
            }
#pragma unroll
            for (int j = 0; j < 4; ++j) {
                int ch = j * NTHR + tid;
                int r2 = ch >> 6, c8 = (ch & 63) * 8;
                xp[j] = *(const f16x8*)&xin[((size_t)(b0r + r2) * T_ + t1) * 512 + c8];
            }
        }
    }
    __syncthreads();

    const int arow = lane & 15;
    const int kc8 = (lane >> 4) * 8;     // f16 offset; u32 offset = (lane>>4)*4

    for (int s = 0; s < T_; ++s) {
        const int t = dir ? (T_ - 1 - s) : s;

        // ---- phase A: x-part MFMAs (weights from VGPRs for L0) ----
        f32x4 acc[NSUB][2];
#pragma unroll
        for (int sub = 0; sub < NSUB; ++sub) {
            f32x4 z = {0.f, 0.f, 0.f, 0.f};
            acc[sub][0] = z; acc[sub][1] = z;
        }
#pragma unroll
        for (int kt = 0; kt < KXT; ++kt) {
            f16x8 a = *(const f16x8*)&a_lds[(size_t)arow * KP + kt * 32 + kc8];
#pragma unroll
            for (int sub = 0; sub < NSUB; ++sub) {
                f16x8 b;
                if constexpr (XREG) b = bx[sub][kt];
                else b = *(const f16x8*)&w_lds[(((size_t)(gt * NSUB + sub) * KT + kt) * 64 + lane) * 8];
                acc[sub][kt & 1] = __builtin_amdgcn_mfma_f32_16x16x32_f16(a, b, acc[sub][kt & 1], 0, 0, 0);
            }
        }

        // ---- phase B: tagged data-poll gather of h(s-1) -> h_lds ----
        if (s > 0 && !skip) {
            const u32 want = (u32)(s - 1);
            u64* bw = hbuf + ((size_t)grp * 2 + ((s - 1) & 1)) * NWORD;
            u64 ga[NW];
            u32 pend = (1u << NW) - 1u;
#pragma unroll
            for (int k = 0; k < NW; ++k)
                ga[k] = __hip_atomic_load(&bw[k * NTHR + tid], __ATOMIC_RELAXED,
                                          __HIP_MEMORY_SCOPE_AGENT);
            for (;;) {
#pragma unroll
                for (int k = 0; k < NW; ++k) {
                    if ((pend & (1u << k)) && (u32)(ga[k] >> 32) == want) {
                        int w = k * NTHR + tid;
                        h32[(size_t)(w >> 7) * HPW + (w & 127)] = (u32)ga[k];
                        pend &= ~(1u << k);
                    }
                }
                if (!pend) break;
#pragma unroll
                for (int k = 0; k < NW; ++k)
                    if (pend & (1u << k))
                        ga[k] = __hip_atomic_load(&bw[k * NTHR + tid], __ATOMIC_RELAXED,
                                                  __HIP_MEMORY_SCOPE_AGENT);
            }
        }
        __syncthreads();   // B1: h_lds ready; phase-A a_lds reads done

        // stage x(s+1) into a_lds (from prefetch regs)
        if constexpr (IS_L0) {
            const int xrow = tid >> 4, c4 = (tid & 15) * 4;
            f16x4 h4; h4[0]=(_Float16)xv.x; h4[1]=(_Float16)xv.y; h4[2]=(_Float16)xv.z; h4[3]=(_Float16)xv.w;
            *(f16x4*)&a_lds[(size_t)xrow * KP + c4] = h4;
        } else {
#pragma unroll
            for (int j = 0; j < 4; ++j) {
                int ch = j * NTHR + tid;
                int r2 = ch >> 6, c8 = (ch & 63) * 8;
                *(f16x8*)&a_lds[(size_t)r2 * KP + c8] = xp[j];
            }
        }

        // ---- phase C: h-part MFMAs from h_lds ----
        if (s > 0) {
#pragma unroll
            for (int kt = 0; kt < KHT; ++kt) {
                f16x8 a = *(const f16x8*)&h32[(size_t)arow * HPW + kt * 16 + (lane >> 4) * 4];
#pragma unroll
                for (int sub = 0; sub < NSUB; ++sub) {
                    f16x8 b;
                    if constexpr (XREG)
                        b = *(const f16x8*)&w_lds[(((size_t)(gt * NSUB + sub) * KHT + kt) * 64 + lane) * 8];
                    else
                        b = *(const f16x8*)&w_lds[(((size_t)(gt * NSUB + sub) * KT + KXT + kt) * 64 + lane) * 8];
                    acc[sub][kt & 1] = __builtin_amdgcn_mfma_f32_16x16x32_f16(a, b, acc[sub][kt & 1], 0, 0, 0);
                }
            }
        }
        {
            const int crow = (lane >> 4) * 4, ccol = lane & 15;
#pragma unroll
            for (int sub = 0; sub < NSUB; ++sub) {
                f32x4 av = acc[sub][0] + acc[sub][1];
#pragma unroll
                for (int qq = 0; qq < 4; ++qq)
                    g_lds[(size_t)(gt * MROWS + crow + qq) * GP + sub * 16 + ccol] = av[qq];
            }
        }
        __syncthreads();   // B2: gates ready; a_lds staged for next step

        // ---- phase D: elementwise; tagged publish; own-h LDS write ----
        float hval[NSUB];
#pragma unroll
        for (int j = 0; j < NSUB; ++j) {
            float gI = g_lds[(size_t)(0 * MROWS + erow) * GP + ecp * NSUB + j] + b_[0][j];
            float gF = g_lds[(size_t)(1 * MROWS + erow) * GP + ecp * NSUB + j] + b_[1][j];
            float gG = g_lds[(size_t)(2 * MROWS + erow) * GP + ecp * NSUB + j] + b_[2][j];
            float gO = g_lds[(size_t)(3 * MROWS + erow) * GP + ecp * NSUB + j] + b_[3][j];
            float i_ = sigm(gI), f_ = sigm(gF), g2 = tanh_(gG), o_ = sigm(gO);
            c_reg[j] = f_ * c_reg[j] + i_ * g2;
            hval[j] = o_ * tanh_(c_reg[j]);
        }
        {
            u64* bw = hbuf + ((size_t)grp * 2 + (s & 1)) * NWORD;
            if constexpr (NSUB == 4) {
                union { _Float16 h[2]; u32 u; } pk0, pk1;
                pk0.h[0] = (_Float16)hval[0]; pk0.h[1] = (_Float16)hval[1];
                pk1.h[0] = (_Float16)hval[2]; pk1.h[1] = (_Float16)hval[3];
                const int wcol = q * 32 + ecp * 2;
                if (s + 1 < T_) {
                    u64 tg = ((u64)(u32)s << 32);
                    __hip_atomic_store(&bw[erow * 128 + wcol], (u64)pk0.u | tg,
                                       __ATOMIC_RELAXED, __HIP_MEMORY_SCOPE_AGENT);
                    __hip_atomic_store(&bw[erow * 128 + wcol + 1], (u64)pk1.u | tg,
                                       __ATOMIC_RELAXED, __HIP_MEMORY_SCOPE_AGENT);
                    h32[(size_t)erow * HPW + wcol] = pk0.u;
                    h32[(size_t)erow * HPW + wcol + 1] = pk1.u;
                }
                if constexpr (IS_L0) {
                    u64 ov = (u64)pk0.u | ((u64)pk1.u << 32);
                    *(u64*)&out0[((size_t)(b0r + erow) * T_ + t) * 512 + dir * 256 + q * QW + ecp * 4] = ov;
                }
            } else if constexpr (NSUB == 2) {
                union { _Float16 h[2]; u32 u; } pk;
                pk.h[0] = (_Float16)hval[0]; pk.h[1] = (_Float16)hval[1];
                if (s + 1 < T_) {
                    u64 word = (u64)pk.u | ((u64)(u32)s << 32);
                    __hip_atomic_store(&bw[erow * 128 + q * 16 + ecp], word,
                                       __ATOMIC_RELAXED, __HIP_MEMORY_SCOPE_AGENT);
                    h32[(size_t)erow * HPW + q * 16 + ecp] = pk.u;
                }
                if constexpr (IS_L0) {
                    *(u32*)&out0[((size_t)(b0r + erow) * T_ + t) * 512 + dir * 256 + q * QW + ecp * 2] = pk.u;
                }
            } else {
                union { _Float16 h; unsigned short u; } hb; hb.h = (_Float16)hval[0];
                u32 ov = (u32)__shfl_xor((int)hb.u, 1);
                u32 lo = (u32)hb.u | ((ov & 0xFFFFu) << 16);
                if (!(lane & 1) && s + 1 < T_) {
                    u64 word = (u64)lo | ((u64)(u32)s << 32);
                    __hip_atomic_store(&bw[erow * 128 + ((q * 16 + ecp) >> 1)], word,
                                       __ATOMIC_RELAXED, __HIP_MEMORY_SCOPE_AGENT);
                    h32[(size_t)erow * HPW + q * (QW / 2) + (ecp >> 1)] = lo;
                }
            }
        }

        // ---- post (off detect path): hlast + x prefetch ----
        if constexpr (!IS_L0) {
            if (s == T_ - 1)
                hlast[(size_t)(b0r + erow) * 256 + q * QW + ecp] = hval[0];
        }
        {
            int sn2 = (s + 2 < T_) ? s + 2 : T_ - 1;
            int t2 = dir ? (T_ - 1 - sn2) : sn2;
            if constexpr (IS_L0) {
                const int xrow = tid >> 4, c4 = (tid & 15) * 4;
                xv = *(const float4*)&x[((size_t)(b0r + xrow) * T_ + t2) * IN_ + c4];
            } else {
#pragma unroll
                for (int j = 0; j < 4; ++j) {
                    int ch = j * NTHR + tid;
                    int r2 = ch >> 6, c8 = (ch & 63) * 8;
                    xp[j] = *(const f16x8*)&xin[((size_t)(b0r + r2) * T_ + t2) * 512 + c8];
                }
            }
        }
    }
}

// layer1 backward single step (t=T-1, zero state) + FC over [h1f | hb]
__global__ __launch_bounds__(256)
void tail_kernel(const _Float16* __restrict__ out0, const float* __restrict__ Wih1,
                 const float* __restrict__ b1, const float* __restrict__ fcw,
                 const float* __restrict__ fcb, const float* __restrict__ h1f,
                 float* __restrict__ out) {
    const int b = blockIdx.x, tid = threadIdx.x;
    __shared__ float xs[512];
    __shared__ float red[256];
    for (int i = tid; i < 512; i += 256)
        xs[i] = (float)out0[((size_t)b * T_ + (T_ - 1)) * 512 + i];
    __syncthreads();
    const float* Wb = Wih1 + (size_t)1024 * 512;  // dir 1
    const float* wI = Wb + (size_t)tid * 512;
    const float* wG = Wb + (size_t)(512 + tid) * 512;
    const float* wO = Wb + (size_t)(768 + tid) * 512;
    float aI = 0.f, aG = 0.f, aO = 0.f;
    for (int k = 0; k < 512; k += 4) {
        float4 xv = *(const float4*)&xs[k];
        float4 w0 = *(const float4*)&wI[k];
        float4 w1 = *(const float4*)&wG[k];
        float4 w2 = *(const float4*)&wO[k];
        aI += xv.x * w0.x + xv.y * w0.y + xv.z * w0.z + xv.w * w0.w;
        aG += xv.x * w1.x + xv.y * w1.y + xv.z * w1.z + xv.w * w1.w;
        aO += xv.x * w2.x + xv.y * w2.y + xv.z * w2.z + xv.w * w2.w;
    }
    float i_ = sigm(aI + b1[1024 + tid]);
    float g_ = tanh_(aG + b1[1024 + 512 + tid]);
    float o_ = sigm(aO + b1[1024 + 768 + tid]);
    float c = i_ * g_;  // c0 = 0
    float hb = o_ * tanh_(c);
    float part = h1f[b * 256 + tid] * fcw[tid] + hb * fcw[256 + tid];
    red[tid] = part;
    __syncthreads();
    for (int sx = 128; sx > 0; sx >>= 1) {
        if (tid < sx) red[tid] += red[tid + sx];
        __syncthreads();
    }
    if (tid == 0) out[b] = red[0] + fcb[0];
}

extern "C" void kernel_launch(void* const* d_in, const int* in_sizes, int n_in,
                              void* d_out, int out_size, void* d_ws, size_t ws_size,
                              hipStream_t stream) {
    const float* x    = (const float*)d_in[0];
    const float* Wih0 = (const float*)d_in[1];
    const float* Whh0 = (const float*)d_in[2];
    const float* b0   = (const float*)d_in[3];
    const float* Wih1 = (const float*)d_in[4];
    const float* Whh1 = (const float*)d_in[5];
    const float* b1   = (const float*)d_in[6];
    const float* fcw  = (const float*)d_in[7];
    const float* fcb  = (const float*)d_in[8];

    char* ws = (char*)d_ws;
    _Float16* W0pack = (_Float16*)(ws + 0);          // 1,310,720 B
    _Float16* W1pack = (_Float16*)(ws + 1310720);    // 1,572,864 B -> 2,883,584
    u64* hbuf0       = (u64*)(ws + 2883584);         // 1,048,576 B
    u64* hbuf1       = (u64*)(ws + 3932160);         //   524,288 B
    float* h1f       = (float*)(ws + 4456448);       //   262,144 B
    _Float16* out0   = (_Float16*)(ws + 4718592);    // 134,217,728 B -> ~138.9 MB

    // poison tag buffers (0xFFFFFFFF != any step); replay-safe
    hipMemsetAsync(ws + 2883584, 0xFF, 1572864, stream);

    // L0: QW=64, NSUB=4, NQ=4, KT=10, dirs=2 -> 655360 elems
    hipLaunchKernelGGL(pack_w, dim3(2560), dim3(256), 0, stream,
                       Wih0, Whh0, W0pack, 64, 256, 10, 64, 4, 4, 655360);
    // L1: QW=16, NSUB=1, NQ=16, KT=24, dirs=1 -> 786432 elems
    hipLaunchKernelGGL(pack_w, dim3(3072), dim3(256), 0, stream,
                       Wih1, Whh1, W1pack, 512, 256, 24, 16, 1, 16, 786432);

    // L0 LDS: 131072(w:h-part) + 8448(h) + 2304(a) + 16640(g) = 158,464
    hipFuncSetAttribute((const void*)(lstm_scan<2, 8, 64, true>),
                        hipFuncAttributeMaxDynamicSharedMemorySize, 158464);
    // L1 LDS: 98304(w) + 8448(h) + 16640(a) + 4352(g) = 127,744
    hipFuncSetAttribute((const void*)(lstm_scan<16, 8, 16, false>),
                        hipFuncAttributeMaxDynamicSharedMemorySize, 127744);

    // L0: 32 groups (2 dir x 16 bg) x 4 col-blocks = 128 blocks
    hipLaunchKernelGGL((lstm_scan<2, 8, 64, true>), dim3(128), dim3(256), 158464, stream,
                       x, (const _Float16*)nullptr, W0pack, b0, hbuf0,
                       out0, (float*)nullptr);
    // L1 fwd: 16 groups x 16 col-blocks = 256 blocks, K=768 folded
    hipLaunchKernelGGL((lstm_scan<16, 8, 16, false>), dim3(256), dim3(256), 127744, stream,
                       (const float*)nullptr, (const _Float16*)out0, W1pack, b1, hbuf1,
                       (_Float16*)nullptr, h1f);
    hipLaunchKernelGGL(tail_kernel, dim3(256), dim3(256), 0, stream,
                       out0, Wih1, b1, fcw, fcb, h1f, (float*)d_out);
}

// Round 13
// 2394.679 us; speedup vs baseline: 2.3837x; 1.0343x over previous
//
#include <hip/hip_runtime.h>

// LSTM_50208167690847 v13: 2-layer BiLSTM (B=256,T=512,IN=64,H=256) + FC.
// v10 -> v13 (v12's QW=64 reverted; volume theory falsified):
//  vmcnt is in-order-retire, so the poll's first check (vmcnt(0)) drained
//  the out0 HBM store + x HBM prefetch issued just before it. Fix (pure
//  issue reorder, protocol/barriers byte-identical to v10):
//   - out0 store of h(s-1) moved from phase D to post-gather (register
//     carried prev_pk/t_prev, epilogue flush)
//   - x prefetch moved from post-D to right after staging
//  Both now retire during C+D+A (~1.3us) instead of sitting on the poll.

#define T_ 512
#define IN_ 64
#define H_ 256

typedef __attribute__((ext_vector_type(8))) _Float16 f16x8;
typedef __attribute__((ext_vector_type(4))) _Float16 f16x4;
typedef __attribute__((ext_vector_type(4))) float f32x4;
typedef unsigned long long u64;
typedef unsigned int u32;

__device__ __forceinline__ float sigm(float x){ return 1.f/(1.f+__expf(-x)); }
__device__ __forceinline__ float tanh_(float x){ return 1.f - 2.f/(__expf(2.f*x)+1.f); }

// pack weights into per-(dir,q) MFMA-B fragment order:
// flat = ((((dir*NQ+q)*4 + gt)*NSUB + sub)*KT + kt)*512 + lane*8 + e
// gate col g = gt*256 + q*QW + sub*16 + (lane&15); k = kt*32 + (lane>>4)*8 + e
__global__ void pack_w(const float* __restrict__ ih, const float* __restrict__ hh,
                       _Float16* __restrict__ dst, int KX, int KH, int KT,
                       int QW, int NSUB, int NQ, int total) {
    int idx = blockIdx.x * 256 + threadIdx.x;
    if (idx >= total) return;
    int e = idx & 7, lane = (idx >> 3) & 63;
    int u = idx >> 9;
    int kt = u % KT; u /= KT;
    int sub = u % NSUB; u /= NSUB;
    int gt = u & 3; u >>= 2;
    int q = u % NQ; int dir = u / NQ;
    int g = gt * 256 + q * QW + sub * 16 + (lane & 15);
    int k = kt * 32 + (lane >> 4) * 8 + e;
    float v = (k < KX) ? ih[(size_t)(dir * 1024 + g) * KX + k]
                       : hh[(size_t)(dir * 1024 + g) * KH + (k - KX)];
    dst[idx] = (_Float16)v;
}

// Block map: grp = bid % NGRP, q = bid / NGRP.
template <int KXT, int KHT, int QW, bool IS_L0>
__global__ __launch_bounds__(256)
void lstm_scan(const float* __restrict__ x, const _Float16* __restrict__ xin,
               const _Float16* __restrict__ wpack, const float* __restrict__ bias,
               u64* __restrict__ hbuf,
               _Float16* __restrict__ out0, float* __restrict__ hlast) {
    constexpr int MROWS = 16;
    constexpr int KT = KXT + KHT, KX = KXT * 32;
    constexpr int NTHR = 256;
    constexpr int NSUB = QW / 16, NQ = 256 / QW;
    constexpr int NGRP = IS_L0 ? 32 : 16;
    constexpr int WBE = 4 * NSUB * KT * 512;    // weight slice elems
    constexpr int KP = KX + 8;                  // a_lds f16 row stride
    constexpr int HPW = 132;                    // h_lds u32 row stride
    constexpr int GP = QW + 1;
    constexpr int NWORD = MROWS * 128;          // u64 words per group-buffer (2048)
    constexpr int NW = NWORD / NTHR;            // words per thread (8)
    constexpr int OWNW = QW / 2;                // own u64-col width

    extern __shared__ char smem[];
    _Float16* w_lds = (_Float16*)smem;
    u32*      h32   = (u32*)(smem + (size_t)WBE * 2);
    _Float16* a_lds = (_Float16*)(smem + (size_t)WBE * 2 + (size_t)MROWS * HPW * 4);
    float*    g_lds = (float*)(smem + (size_t)WBE * 2 + (size_t)MROWS * HPW * 4
                               + (size_t)MROWS * KP * 2);

    const int tid = threadIdx.x, lane = tid & 63, wave = tid >> 6;
    const int grp = blockIdx.x % NGRP, q = blockIdx.x / NGRP;
    const int dir = IS_L0 ? (grp >> 4) : 0;
    const int b0r = (IS_L0 ? (grp & 15) : grp) * MROWS;
    const int gt = wave;                        // wave == gate

    // stage weight slice into LDS (once)
    {
        const f16x8* src = (const f16x8*)(wpack + (size_t)(dir * NQ + q) * WBE);
        f16x8* dst = (f16x8*)w_lds;
        for (int i = tid; i < WBE / 8; i += NTHR) dst[i] = src[i];
    }

    // elementwise mapping: thread -> (row erow, NSUB cols at q*QW + ecp*NSUB)
    const int erow = tid >> 4, ecp = tid & 15;
    float b_[4][NSUB], c_reg[NSUB];
#pragma unroll
    for (int g4 = 0; g4 < 4; ++g4)
#pragma unroll
        for (int j = 0; j < NSUB; ++j)
            b_[g4][j] = bias[dir * 1024 + g4 * 256 + q * QW + ecp * NSUB + j];
#pragma unroll
    for (int j = 0; j < NSUB; ++j) c_reg[j] = 0.f;

    // gather role: each thread's NW words share col-pair colp = tid & 127
    const int colp = tid & 127;
    const bool skip = (colp >= q * OWNW) && (colp < q * OWNW + OWNW);

    // x staging: t0 into a_lds, t1 prefetched to regs
    float4 xv;            // L0
    f16x8 xp[4];          // L1
    {
        int t0 = dir ? (T_ - 1) : 0;
        int t1 = dir ? (T_ - 2) : 1;
        if constexpr (IS_L0) {
            const int xrow = tid >> 4, c4 = (tid & 15) * 4;
            float4 v0 = *(const float4*)&x[((size_t)(b0r + xrow) * T_ + t0) * IN_ + c4];
            f16x4 h4; h4[0]=(_Float16)v0.x; h4[1]=(_Float16)v0.y; h4[2]=(_Float16)v0.z; h4[3]=(_Float16)v0.w;
            *(f16x4*)&a_lds[(size_t)xrow * KP + c4] = h4;
            xv = *(const float4*)&x[((size_t)(b0r + xrow) * T_ + t1) * IN_ + c4];
        } else {
#pragma unroll
            for (int j = 0; j < 4; ++j) {
                int ch = j * NTHR + tid;
                int r2 = ch >> 6, c8 = (ch & 63) * 8;
                f16x8 v = *(const f16x8*)&xin[((size_t)(b0r + r2) * T_ + t0) * 512 + c8];
                *(f16x8*)&a_lds[(size_t)r2 * KP + c8] = v;
            }
#pragma unroll
            for (int j = 0; j < 4; ++j) {
                int ch = j * NTHR + tid;
                int r2 = ch >> 6, c8 = (ch & 63) * 8;
                xp[j] = *(const f16x8*)&xin[((size_t)(b0r + r2) * T_ + t1) * 512 + c8];
            }
        }
    }
    __syncthreads();

    const int arow = lane & 15;
    const int kc8 = (lane >> 4) * 8;     // f16 offset; u32 offset = (lane>>4)*4

    u32 prev_pk = 0;                     // L0: packed h(s-1) for deferred out0
    int t_prev = 0;

    for (int s = 0; s < T_; ++s) {
        const int t = dir ? (T_ - 1 - s) : s;

        // ---- phase A: x-part MFMAs (independent of peers' h) ----
        f32x4 acc[NSUB][2];
#pragma unroll
        for (int sub = 0; sub < NSUB; ++sub) {
            f32x4 z = {0.f, 0.f, 0.f, 0.f};
            acc[sub][0] = z; acc[sub][1] = z;
        }
#pragma unroll
        for (int kt = 0; kt < KXT; ++kt) {
            f16x8 a = *(const f16x8*)&a_lds[(size_t)arow * KP + kt * 32 + kc8];
#pragma unroll
            for (int sub = 0; sub < NSUB; ++sub) {
                f16x8 b = *(const f16x8*)&w_lds[(((size_t)(gt * NSUB + sub) * KT + kt) * 64 + lane) * 8];
                acc[sub][kt & 1] = __builtin_amdgcn_mfma_f32_16x16x32_f16(a, b, acc[sub][kt & 1], 0, 0, 0);
            }
        }

        // ---- phase B: tagged data-poll gather of h(s-1) -> h_lds ----
        // (no HBM ops outstanding from this wave: poll's vmcnt only covers
        //  the fabric publish issued last step)
        if (s > 0 && !skip) {
            const u32 want = (u32)(s - 1);
            u64* bw = hbuf + ((size_t)grp * 2 + ((s - 1) & 1)) * NWORD;
            u64 ga[NW];
            u32 pend = (1u << NW) - 1u;
#pragma unroll
            for (int k = 0; k < NW; ++k)
                ga[k] = __hip_atomic_load(&bw[k * NTHR + tid], __ATOMIC_RELAXED,
                                          __HIP_MEMORY_SCOPE_AGENT);
            for (;;) {
#pragma unroll
                for (int k = 0; k < NW; ++k) {
                    if ((pend & (1u << k)) && (u32)(ga[k] >> 32) == want) {
                        int w = k * NTHR + tid;
                        h32[(size_t)(w >> 7) * HPW + (w & 127)] = (u32)ga[k];
                        pend &= ~(1u << k);
                    }
                }
                if (!pend) break;
#pragma unroll
                for (int k = 0; k < NW; ++k)
                    if (pend & (1u << k))
                        ga[k] = __hip_atomic_load(&bw[k * NTHR + tid], __ATOMIC_RELAXED,
                                                  __HIP_MEMORY_SCOPE_AGENT);
            }
        }

        // ---- post-gather: slow HBM store of h(s-1) (off next poll's drain) ----
        if constexpr (IS_L0) {
            if (s > 0)
                *(u32*)&out0[((size_t)(b0r + erow) * T_ + t_prev) * 512 + dir * 256 + q * QW + ecp * 2] = prev_pk;
        }
        __syncthreads();   // B1: h_lds ready; phase-A a_lds reads done

        // stage x(s+1) into a_lds (from prefetch regs)
        if constexpr (IS_L0) {
            const int xrow = tid >> 4, c4 = (tid & 15) * 4;
            f16x4 h4; h4[0]=(_Float16)xv.x; h4[1]=(_Float16)xv.y; h4[2]=(_Float16)xv.z; h4[3]=(_Float16)xv.w;
            *(f16x4*)&a_lds[(size_t)xrow * KP + c4] = h4;
        } else {
#pragma unroll
            for (int j = 0; j < 4; ++j) {
                int ch = j * NTHR + tid;
                int r2 = ch >> 6, c8 = (ch & 63) * 8;
                *(f16x8*)&a_lds[(size_t)r2 * KP + c8] = xp[j];
            }
        }
        // prefetch x(s+2) NOW (regs just freed); retires during C+D+A
        {
            int sn2 = (s + 2 < T_) ? s + 2 : T_ - 1;
            int t2 = dir ? (T_ - 1 - sn2) : sn2;
            if constexpr (IS_L0) {
                const int xrow = tid >> 4, c4 = (tid & 15) * 4;
                xv = *(const float4*)&x[((size_t)(b0r + xrow) * T_ + t2) * IN_ + c4];
            } else {
#pragma unroll
                for (int j = 0; j < 4; ++j) {
                    int ch = j * NTHR + tid;
                    int r2 = ch >> 6, c8 = (ch & 63) * 8;
                    xp[j] = *(const f16x8*)&xin[((size_t)(b0r + r2) * T_ + t2) * 512 + c8];
                }
            }
        }

        // ---- phase C: h-part MFMAs from h_lds ----
        if (s > 0) {
#pragma unroll
            for (int kt = 0; kt < KHT; ++kt) {
                f16x8 a = *(const f16x8*)&h32[(size_t)arow * HPW + kt * 16 + (lane >> 4) * 4];
#pragma unroll
                for (int sub = 0; sub < NSUB; ++sub) {
                    f16x8 b = *(const f16x8*)&w_lds[(((size_t)(gt * NSUB + sub) * KT + KXT + kt) * 64 + lane) * 8];
                    acc[sub][kt & 1] = __builtin_amdgcn_mfma_f32_16x16x32_f16(a, b, acc[sub][kt & 1], 0, 0, 0);
                }
            }
        }
        {
            const int crow = (lane >> 4) * 4, ccol = lane & 15;
#pragma unroll
            for (int sub = 0; sub < NSUB; ++sub) {
                f32x4 av = acc[sub][0] + acc[sub][1];
#pragma unroll
                for (int qq = 0; qq < 4; ++qq)
                    g_lds[(size_t)(gt * MROWS + crow + qq) * GP + sub * 16 + ccol] = av[qq];
            }
        }
        __syncthreads();   // B2: gates ready; a_lds staged for next step

        // ---- phase D: elementwise; tagged publish; own-h LDS write ----
        float hval[NSUB];
#pragma unroll
        for (int j = 0; j < NSUB; ++j) {
            float gI = g_lds[(size_t)(0 * MROWS + erow) * GP + ecp * NSUB + j] + b_[0][j];
            float gF = g_lds[(size_t)(1 * MROWS + erow) * GP + ecp * NSUB + j] + b_[1][j];
            float gG = g_lds[(size_t)(2 * MROWS + erow) * GP + ecp * NSUB + j] + b_[2][j];
            float gO = g_lds[(size_t)(3 * MROWS + erow) * GP + ecp * NSUB + j] + b_[3][j];
            float i_ = sigm(gI), f_ = sigm(gF), g2 = tanh_(gG), o_ = sigm(gO);
            c_reg[j] = f_ * c_reg[j] + i_ * g2;
            hval[j] = o_ * tanh_(c_reg[j]);
        }
        {
            u64* bw = hbuf + ((size_t)grp * 2 + (s & 1)) * NWORD;
            if constexpr (NSUB == 2) {
                union { _Float16 h[2]; u32 u; } pk;
                pk.h[0] = (_Float16)hval[0]; pk.h[1] = (_Float16)hval[1];
                if (s + 1 < T_) {
                    u64 word = (u64)pk.u | ((u64)(u32)s << 32);
                    __hip_atomic_store(&bw[erow * 128 + q * 16 + ecp], word,
                                       __ATOMIC_RELAXED, __HIP_MEMORY_SCOPE_AGENT);
                    h32[(size_t)erow * HPW + q * 16 + ecp] = pk.u;
                }
                prev_pk = pk.u;          // deferred out0 store (post-gather s+1)
                t_prev = t;
            } else {
                union { _Float16 h; unsigned short u; } hb; hb.h = (_Float16)hval[0];
                u32 ov = (u32)__shfl_xor((int)hb.u, 1);
                u32 lo = (u32)hb.u | ((ov & 0xFFFFu) << 16);
                if (!(lane & 1) && s + 1 < T_) {
                    u64 word = (u64)lo | ((u64)(u32)s << 32);
                    __hip_atomic_store(&bw[erow * 128 + ((q * 16 + ecp) >> 1)], word,
                                       __ATOMIC_RELAXED, __HIP_MEMORY_SCOPE_AGENT);
                    h32[(size_t)erow * HPW + q * (QW / 2) + (ecp >> 1)] = lo;
                }
            }
        }
        if constexpr (!IS_L0) {
            if (s == T_ - 1)
                hlast[(size_t)(b0r + erow) * 256 + q * QW + ecp] = hval[0];
        }
    }

    // epilogue: flush the last deferred out0 value (h(T-1))
    if constexpr (IS_L0) {
        *(u32*)&out0[((size_t)(b0r + erow) * T_ + t_prev) * 512 + dir * 256 + q * QW + ecp * 2] = prev_pk;
    }
}

// layer1 backward single step (t=T-1, zero state) + FC over [h1f | hb]
__global__ __launch_bounds__(256)
void tail_kernel(const _Float16* __restrict__ out0, const float* __restrict__ Wih1,
                 const float* __restrict__ b1, const float* __restrict__ fcw,
                 const float* __restrict__ fcb, const float* __restrict__ h1f,
                 float* __restrict__ out) {
    const int b = blockIdx.x, tid = threadIdx.x;
    __shared__ float xs[512];
    __shared__ float red[256];
    for (int i = tid; i < 512; i += 256)
        xs[i] = (float)out0[((size_t)b * T_ + (T_ - 1)) * 512 + i];
    __syncthreads();
    const float* Wb = Wih1 + (size_t)1024 * 512;  // dir 1
    const float* wI = Wb + (size_t)tid * 512;
    const float* wG = Wb + (size_t)(512 + tid) * 512;
    const float* wO = Wb + (size_t)(768 + tid) * 512;
    float aI = 0.f, aG = 0.f, aO = 0.f;
    for (int k = 0; k < 512; k += 4) {
        float4 xv = *(const float4*)&xs[k];
        float4 w0 = *(const float4*)&wI[k];
        float4 w1 = *(const float4*)&wG[k];
        float4 w2 = *(const float4*)&wO[k];
        aI += xv.x * w0.x + xv.y * w0.y + xv.z * w0.z + xv.w * w0.w;
        aG += xv.x * w1.x + xv.y * w1.y + xv.z * w1.z + xv.w * w1.w;
        aO += xv.x * w2.x + xv.y * w2.y + xv.z * w2.z + xv.w * w2.w;
    }
    float i_ = sigm(aI + b1[1024 + tid]);
    float g_ = tanh_(aG + b1[1024 + 512 + tid]);
    float o_ = sigm(aO + b1[1024 + 768 + tid]);
    float c = i_ * g_;  // c0 = 0
    float hb = o_ * tanh_(c);
    float part = h1f[b * 256 + tid] * fcw[tid] + hb * fcw[256 + tid];
    red[tid] = part;
    __syncthreads();
    for (int sx = 128; sx > 0; sx >>= 1) {
        if (tid < sx) red[tid] += red[tid + sx];
        __syncthreads();
    }
    if (tid == 0) out[b] = red[0] + fcb[0];
}

extern "C" void kernel_launch(void* const* d_in, const int* in_sizes, int n_in,
                              void* d_out, int out_size, void* d_ws, size_t ws_size,
                              hipStream_t stream) {
    const float* x    = (const float*)d_in[0];
    const float* Wih0 = (const float*)d_in[1];
    const float* Whh0 = (const float*)d_in[2];
    const float* b0   = (const float*)d_in[3];
    const float* Wih1 = (const float*)d_in[4];
    const float* Whh1 = (const float*)d_in[5];
    const float* b1   = (const float*)d_in[6];
    const float* fcw  = (const float*)d_in[7];
    const float* fcb  = (const float*)d_in[8];

    char* ws = (char*)d_ws;
    _Float16* W0pack = (_Float16*)(ws + 0);          // 1,310,720 B
    _Float16* W1pack = (_Float16*)(ws + 1310720);    // 1,572,864 B -> 2,883,584
    u64* hbuf0       = (u64*)(ws + 2883584);         // 1,048,576 B
    u64* hbuf1       = (u64*)(ws + 3932160);         //   524,288 B
    float* h1f       = (float*)(ws + 4456448);       //   262,144 B
    _Float16* out0   = (_Float16*)(ws + 4718592);    // 134,217,728 B -> ~138.9 MB

    // poison tag buffers (0xFFFFFFFF != any step); replay-safe
    hipMemsetAsync(ws + 2883584, 0xFF, 1572864, stream);

    // L0: QW=32, NSUB=2, NQ=8, KT=10, dirs=2 -> 655360 elems
    hipLaunchKernelGGL(pack_w, dim3(2560), dim3(256), 0, stream,
                       Wih0, Whh0, W0pack, 64, 256, 10, 32, 2, 8, 655360);
    // L1: QW=16, NSUB=1, NQ=16, KT=24, dirs=1 -> 786432 elems
    hipLaunchKernelGGL(pack_w, dim3(3072), dim3(256), 0, stream,
                       Wih1, Whh1, W1pack, 512, 256, 24, 16, 1, 16, 786432);

    // L0 LDS: 81920(w) + 8448(h) + 2304(a) + 8448(g) = 101,120 -> 1 blk/CU
    hipFuncSetAttribute((const void*)(lstm_scan<2, 8, 32, true>),
                        hipFuncAttributeMaxDynamicSharedMemorySize, 101120);
    // L1 LDS: 98304(w) + 8448(h) + 16640(a) + 4352(g) = 127,744 -> 1 blk/CU
    hipFuncSetAttribute((const void*)(lstm_scan<16, 8, 16, false>),
                        hipFuncAttributeMaxDynamicSharedMemorySize, 127744);

    // L0: 32 groups (2 dir x 16 bg, M=16) x 8 col-blocks = 256 blocks
    hipLaunchKernelGGL((lstm_scan<2, 8, 32, true>), dim3(256), dim3(256), 101120, stream,
                       x, (const _Float16*)nullptr, W0pack, b0, hbuf0,
                       out0, (float*)nullptr);
    // L1 fwd: 16 groups (M=16) x 16 col-blocks = 256 blocks, K=768 folded
    hipLaunchKernelGGL((lstm_scan<16, 8, 16, false>), dim3(256), dim3(256), 127744, stream,
                       (const float*)nullptr, (const _Float16*)out0, W1pack, b1, hbuf1,
                       (_Float16*)nullptr, h1f);
    hipLaunchKernelGGL(tail_kernel, dim3(256), dim3(256), 0, stream,
                       out0, Wih1, b1, fcw, fcb, h1f, (float*)d_out);
}

// Round 14
// 2128.368 us; speedup vs baseline: 2.6820x; 1.1251x over previous
//
#include <hip/hip_runtime.h>

// LSTM_50208167690847 v14: 2-layer BiLSTM (B=256,T=512,IN=64,H=256) + FC.
// v10 + timed sampling (v13 reorder reverted; drain theory falsified):
//  - s_sleep before issuing the first poll samples: L0 ~640cy, L1 ~256cy.
//    All group peers publish in lockstep; L0's short phase A sampled the
//    fabric right at the publish-visibility edge (~50% stale -> retry RTT).
//    Delaying the ISSUE (the read happens at issue+half-RTT) lands the
//    sample in the fresh window -> 1 RTT instead of 2.
//  - L0 groups phase-staggered at startup ((grp&3) x ~0.2us) to spread
//    independent chains' fabric-atomic bursts (queueing relief).
// Everything else byte-identical to v10 (best: 2304us).

#define T_ 512
#define IN_ 64
#define H_ 256

typedef __attribute__((ext_vector_type(8))) _Float16 f16x8;
typedef __attribute__((ext_vector_type(4))) _Float16 f16x4;
typedef __attribute__((ext_vector_type(4))) float f32x4;
typedef unsigned long long u64;
typedef unsigned int u32;

__device__ __forceinline__ float sigm(float x){ return 1.f/(1.f+__expf(-x)); }
__device__ __forceinline__ float tanh_(float x){ return 1.f - 2.f/(__expf(2.f*x)+1.f); }

// pack weights into per-(dir,q) MFMA-B fragment order:
// flat = ((((dir*NQ+q)*4 + gt)*NSUB + sub)*KT + kt)*512 + lane*8 + e
// gate col g = gt*256 + q*QW + sub*16 + (lane&15); k = kt*32 + (lane>>4)*8 + e
__global__ void pack_w(const float* __restrict__ ih, const float* __restrict__ hh,
                       _Float16* __restrict__ dst, int KX, int KH, int KT,
                       int QW, int NSUB, int NQ, int total) {
    int idx = blockIdx.x * 256 + threadIdx.x;
    if (idx >= total) return;
    int e = idx & 7, lane = (idx >> 3) & 63;
    int u = idx >> 9;
    int kt = u % KT; u /= KT;
    int sub = u % NSUB; u /= NSUB;
    int gt = u & 3; u >>= 2;
    int q = u % NQ; int dir = u / NQ;
    int g = gt * 256 + q * QW + sub * 16 + (lane & 15);
    int k = kt * 32 + (lane >> 4) * 8 + e;
    float v = (k < KX) ? ih[(size_t)(dir * 1024 + g) * KX + k]
                       : hh[(size_t)(dir * 1024 + g) * KH + (k - KX)];
    dst[idx] = (_Float16)v;
}

// Block map: grp = bid % NGRP, q = bid / NGRP.
template <int KXT, int KHT, int QW, bool IS_L0>
__global__ __launch_bounds__(256)
void lstm_scan(const float* __restrict__ x, const _Float16* __restrict__ xin,
               const _Float16* __restrict__ wpack, const float* __restrict__ bias,
               u64* __restrict__ hbuf,
               _Float16* __restrict__ out0, float* __restrict__ hlast) {
    constexpr int MROWS = 16;
    constexpr int KT = KXT + KHT, KX = KXT * 32;
    constexpr int NTHR = 256;
    constexpr int NSUB = QW / 16, NQ = 256 / QW;
    constexpr int NGRP = IS_L0 ? 32 : 16;
    constexpr int WBE = 4 * NSUB * KT * 512;    // weight slice elems
    constexpr int KP = KX + 8;                  // a_lds f16 row stride
    constexpr int HPW = 132;                    // h_lds u32 row stride
    constexpr int GP = QW + 1;
    constexpr int NWORD = MROWS * 128;          // u64 words per group-buffer (2048)
    constexpr int NW = NWORD / NTHR;            // words per thread (8)
    constexpr int OWNW = QW / 2;                // own u64-col width

    extern __shared__ char smem[];
    _Float16* w_lds = (_Float16*)smem;
    u32*      h32   = (u32*)(smem + (size_t)WBE * 2);
    _Float16* a_lds = (_Float16*)(smem + (size_t)WBE * 2 + (size_t)MROWS * HPW * 4);
    float*    g_lds = (float*)(smem + (size_t)WBE * 2 + (size_t)MROWS * HPW * 4
                               + (size_t)MROWS * KP * 2);

    const int tid = threadIdx.x, lane = tid & 63, wave = tid >> 6;
    const int grp = blockIdx.x % NGRP, q = blockIdx.x / NGRP;
    const int dir = IS_L0 ? (grp >> 4) : 0;
    const int b0r = (IS_L0 ? (grp & 15) : grp) * MROWS;
    const int gt = wave;                        // wave == gate

    // stage weight slice into LDS (once)
    {
        const f16x8* src = (const f16x8*)(wpack + (size_t)(dir * NQ + q) * WBE);
        f16x8* dst = (f16x8*)w_lds;
        for (int i = tid; i < WBE / 8; i += NTHR) dst[i] = src[i];
    }

    // elementwise mapping: thread -> (row erow, NSUB cols at q*QW + ecp*NSUB)
    const int erow = tid >> 4, ecp = tid & 15;
    float b_[4][NSUB], c_reg[NSUB];
#pragma unroll
    for (int g4 = 0; g4 < 4; ++g4)
#pragma unroll
        for (int j = 0; j < NSUB; ++j)
            b_[g4][j] = bias[dir * 1024 + g4 * 256 + q * QW + ecp * NSUB + j];
#pragma unroll
    for (int j = 0; j < NSUB; ++j) c_reg[j] = 0.f;

    // gather role: each thread's NW words share col-pair colp = tid & 127
    const int colp = tid & 127;
    const bool skip = (colp >= q * OWNW) && (colp < q * OWNW + OWNW);

    // x staging: t0 into a_lds, t1 prefetched to regs
    float4 xv;            // L0
    f16x8 xp[4];          // L1
    {
        int t0 = dir ? (T_ - 1) : 0;
        int t1 = dir ? (T_ - 2) : 1;
        if constexpr (IS_L0) {
            const int xrow = tid >> 4, c4 = (tid & 15) * 4;
            float4 v0 = *(const float4*)&x[((size_t)(b0r + xrow) * T_ + t0) * IN_ + c4];
            f16x4 h4; h4[0]=(_Float16)v0.x; h4[1]=(_Float16)v0.y; h4[2]=(_Float16)v0.z; h4[3]=(_Float16)v0.w;
            *(f16x4*)&a_lds[(size_t)xrow * KP + c4] = h4;
            xv = *(const float4*)&x[((size_t)(b0r + xrow) * T_ + t1) * IN_ + c4];
        } else {
#pragma unroll
            for (int j = 0; j < 4; ++j) {
                int ch = j * NTHR + tid;
                int r2 = ch >> 6, c8 = (ch & 63) * 8;
                f16x8 v = *(const f16x8*)&xin[((size_t)(b0r + r2) * T_ + t0) * 512 + c8];
                *(f16x8*)&a_lds[(size_t)r2 * KP + c8] = v;
            }
#pragma unroll
            for (int j = 0; j < 4; ++j) {
                int ch = j * NTHR + tid;
                int r2 = ch >> 6, c8 = (ch & 63) * 8;
                xp[j] = *(const f16x8*)&xin[((size_t)(b0r + r2) * T_ + t1) * 512 + c8];
            }
        }
    }
    __syncthreads();

    // one-time group phase stagger (L0: 32 independent chains share fabric)
    if constexpr (IS_L0) {
        for (int i = 0; i < (grp & 3); ++i) __builtin_amdgcn_s_sleep(8);
    }

    const int arow = lane & 15;
    const int kc8 = (lane >> 4) * 8;     // f16 offset; u32 offset = (lane>>4)*4

    for (int s = 0; s < T_; ++s) {
        const int t = dir ? (T_ - 1 - s) : s;

        // ---- phase A: x-part MFMAs (independent of peers' h) ----
        f32x4 acc[NSUB][2];
#pragma unroll
        for (int sub = 0; sub < NSUB; ++sub) {
            f32x4 z = {0.f, 0.f, 0.f, 0.f};
            acc[sub][0] = z; acc[sub][1] = z;
        }
#pragma unroll
        for (int kt = 0; kt < KXT; ++kt) {
            f16x8 a = *(const f16x8*)&a_lds[(size_t)arow * KP + kt * 32 + kc8];
#pragma unroll
            for (int sub = 0; sub < NSUB; ++sub) {
                f16x8 b = *(const f16x8*)&w_lds[(((size_t)(gt * NSUB + sub) * KT + kt) * 64 + lane) * 8];
                acc[sub][kt & 1] = __builtin_amdgcn_mfma_f32_16x16x32_f16(a, b, acc[sub][kt & 1], 0, 0, 0);
            }
        }

        // ---- phase B: tagged data-poll gather of h(s-1) -> h_lds ----
        if (s > 0) {
            // delay the ISSUE so the fabric-side read lands after peers'
            // publishes become visible (fresh first sample -> 1 RTT)
            if constexpr (IS_L0) __builtin_amdgcn_s_sleep(10);
            else                 __builtin_amdgcn_s_sleep(4);
            if (!skip) {
                const u32 want = (u32)(s - 1);
                u64* bw = hbuf + ((size_t)grp * 2 + ((s - 1) & 1)) * NWORD;
                u64 ga[NW];
                u32 pend = (1u << NW) - 1u;
#pragma unroll
                for (int k = 0; k < NW; ++k)
                    ga[k] = __hip_atomic_load(&bw[k * NTHR + tid], __ATOMIC_RELAXED,
                                              __HIP_MEMORY_SCOPE_AGENT);
                for (;;) {
#pragma unroll
                    for (int k = 0; k < NW; ++k) {
                        if ((pend & (1u << k)) && (u32)(ga[k] >> 32) == want) {
                            int w = k * NTHR + tid;
                            h32[(size_t)(w >> 7) * HPW + (w & 127)] = (u32)ga[k];
                            pend &= ~(1u << k);
                        }
                    }
                    if (!pend) break;
#pragma unroll
                    for (int k = 0; k < NW; ++k)
                        if (pend & (1u << k))
                            ga[k] = __hip_atomic_load(&bw[k * NTHR + tid], __ATOMIC_RELAXED,
                                                      __HIP_MEMORY_SCOPE_AGENT);
                }
            }
        }
        __syncthreads();   // B1: h_lds ready; phase-A a_lds reads done

        // stage x(s+1) into a_lds (from prefetch regs)
        if constexpr (IS_L0) {
            const int xrow = tid >> 4, c4 = (tid & 15) * 4;
            f16x4 h4; h4[0]=(_Float16)xv.x; h4[1]=(_Float16)xv.y; h4[2]=(_Float16)xv.z; h4[3]=(_Float16)xv.w;
            *(f16x4*)&a_lds[(size_t)xrow * KP + c4] = h4;
        } else {
#pragma unroll
            for (int j = 0; j < 4; ++j) {
                int ch = j * NTHR + tid;
                int r2 = ch >> 6, c8 = (ch & 63) * 8;
                *(f16x8*)&a_lds[(size_t)r2 * KP + c8] = xp[j];
            }
        }

        // ---- phase C: h-part MFMAs from h_lds ----
        if (s > 0) {
#pragma unroll
            for (int kt = 0; kt < KHT; ++kt) {
                f16x8 a = *(const f16x8*)&h32[(size_t)arow * HPW + kt * 16 + (lane >> 4) * 4];
#pragma unroll
                for (int sub = 0; sub < NSUB; ++sub) {
                    f16x8 b = *(const f16x8*)&w_lds[(((size_t)(gt * NSUB + sub) * KT + KXT + kt) * 64 + lane) * 8];
                    acc[sub][kt & 1] = __builtin_amdgcn_mfma_f32_16x16x32_f16(a, b, acc[sub][kt & 1], 0, 0, 0);
                }
            }
        }
        {
            const int crow = (lane >> 4) * 4, ccol = lane & 15;
#pragma unroll
            for (int sub = 0; sub < NSUB; ++sub) {
                f32x4 av = acc[sub][0] + acc[sub][1];
#pragma unroll
                for (int qq = 0; qq < 4; ++qq)
                    g_lds[(size_t)(gt * MROWS + crow + qq) * GP + sub * 16 + ccol] = av[qq];
            }
        }
        __syncthreads();   // B2: gates ready; a_lds staged for next step

        // ---- phase D: elementwise; tagged publish; own-h LDS write ----
        float hval[NSUB];
#pragma unroll
        for (int j = 0; j < NSUB; ++j) {
            float gI = g_lds[(size_t)(0 * MROWS + erow) * GP + ecp * NSUB + j] + b_[0][j];
            float gF = g_lds[(size_t)(1 * MROWS + erow) * GP + ecp * NSUB + j] + b_[1][j];
            float gG = g_lds[(size_t)(2 * MROWS + erow) * GP + ecp * NSUB + j] + b_[2][j];
            float gO = g_lds[(size_t)(3 * MROWS + erow) * GP + ecp * NSUB + j] + b_[3][j];
            float i_ = sigm(gI), f_ = sigm(gF), g2 = tanh_(gG), o_ = sigm(gO);
            c_reg[j] = f_ * c_reg[j] + i_ * g2;
            hval[j] = o_ * tanh_(c_reg[j]);
        }
        {
            u64* bw = hbuf + ((size_t)grp * 2 + (s & 1)) * NWORD;
            if constexpr (NSUB == 2) {
                union { _Float16 h[2]; u32 u; } pk;
                pk.h[0] = (_Float16)hval[0]; pk.h[1] = (_Float16)hval[1];
                if (s + 1 < T_) {
                    u64 word = (u64)pk.u | ((u64)(u32)s << 32);
                    __hip_atomic_store(&bw[erow * 128 + q * 16 + ecp], word,
                                       __ATOMIC_RELAXED, __HIP_MEMORY_SCOPE_AGENT);
                    h32[(size_t)erow * HPW + q * 16 + ecp] = pk.u;
                }
                if constexpr (IS_L0) {
                    *(u32*)&out0[((size_t)(b0r + erow) * T_ + t) * 512 + dir * 256 + q * QW + ecp * 2] = pk.u;
                }
            } else {
                union { _Float16 h; unsigned short u; } hb; hb.h = (_Float16)hval[0];
                u32 ov = (u32)__shfl_xor((int)hb.u, 1);
                u32 lo = (u32)hb.u | ((ov & 0xFFFFu) << 16);
                if (!(lane & 1) && s + 1 < T_) {
                    u64 word = (u64)lo | ((u64)(u32)s << 32);
                    __hip_atomic_store(&bw[erow * 128 + ((q * 16 + ecp) >> 1)], word,
                                       __ATOMIC_RELAXED, __HIP_MEMORY_SCOPE_AGENT);
                    h32[(size_t)erow * HPW + q * (QW / 2) + (ecp >> 1)] = lo;
                }
            }
        }

        // ---- post (off detect path): hlast + x prefetch ----
        if constexpr (!IS_L0) {
            if (s == T_ - 1)
                hlast[(size_t)(b0r + erow) * 256 + q * QW + ecp] = hval[0];
        }
        {
            int sn2 = (s + 2 < T_) ? s + 2 : T_ - 1;
            int t2 = dir ? (T_ - 1 - sn2) : sn2;
            if constexpr (IS_L0) {
                const int xrow = tid >> 4, c4 = (tid & 15) * 4;
                xv = *(const float4*)&x[((size_t)(b0r + xrow) * T_ + t2) * IN_ + c4];
            } else {
#pragma unroll
                for (int j = 0; j < 4; ++j) {
                    int ch = j * NTHR + tid;
                    int r2 = ch >> 6, c8 = (ch & 63) * 8;
                    xp[j] = *(const f16x8*)&xin[((size_t)(b0r + r2) * T_ + t2) * 512 + c8];
                }
            }
        }
    }
}

// layer1 backward single step (t=T-1, zero state) + FC over [h1f | hb]
__global__ __launch_bounds__(256)
void tail_kernel(const _Float16* __restrict__ out0, const float* __restrict__ Wih1,
                 const float* __restrict__ b1, const float* __restrict__ fcw,
                 const float* __restrict__ fcb, const float* __restrict__ h1f,
                 float* __restrict__ out) {
    const int b = blockIdx.x, tid = threadIdx.x;
    __shared__ float xs[512];
    __shared__ float red[256];
    for (int i = tid; i < 512; i += 256)
        xs[i] = (float)out0[((size_t)b * T_ + (T_ - 1)) * 512 + i];
    __syncthreads();
    const float* Wb = Wih1 + (size_t)1024 * 512;  // dir 1
    const float* wI = Wb + (size_t)tid * 512;
    const float* wG = Wb + (size_t)(512 + tid) * 512;
    const float* wO = Wb + (size_t)(768 + tid) * 512;
    float aI = 0.f, aG = 0.f, aO = 0.f;
    for (int k = 0; k < 512; k += 4) {
        float4 xv = *(const float4*)&xs[k];
        float4 w0 = *(const float4*)&wI[k];
        float4 w1 = *(const float4*)&wG[k];
        float4 w2 = *(const float4*)&wO[k];
        aI += xv.x * w0.x + xv.y * w0.y + xv.z * w0.z + xv.w * w0.w;
        aG += xv.x * w1.x + xv.y * w1.y + xv.z * w1.z + xv.w * w1.w;
        aO += xv.x * w2.x + xv.y * w2.y + xv.z * w2.z + xv.w * w2.w;
    }
    float i_ = sigm(aI + b1[1024 + tid]);
    float g_ = tanh_(aG + b1[1024 + 512 + tid]);
    float o_ = sigm(aO + b1[1024 + 768 + tid]);
    float c = i_ * g_;  // c0 = 0
    float hb = o_ * tanh_(c);
    float part = h1f[b * 256 + tid] * fcw[tid] + hb * fcw[256 + tid];
    red[tid] = part;
    __syncthreads();
    for (int sx = 128; sx > 0; sx >>= 1) {
        if (tid < sx) red[tid] += red[tid + sx];
        __syncthreads();
    }
    if (tid == 0) out[b] = red[0] + fcb[0];
}

extern "C" void kernel_launch(void* const* d_in, const int* in_sizes, int n_in,
                              void* d_out, int out_size, void* d_ws, size_t ws_size,
                              hipStream_t stream) {
    const float* x    = (const float*)d_in[0];
    const float* Wih0 = (const float*)d_in[1];
    const float* Whh0 = (const float*)d_in[2];
    const float* b0   = (const float*)d_in[3];
    const float* Wih1 = (const float*)d_in[4];
    const float* Whh1 = (const float*)d_in[5];
    const float* b1   = (const float*)d_in[6];
    const float* fcw  = (const float*)d_in[7];
    const float* fcb  = (const float*)d_in[8];

    char* ws = (char*)d_ws;
    _Float16* W0pack = (_Float16*)(ws + 0);          // 1,310,720 B
    _Float16* W1pack = (_Float16*)(ws + 1310720);    // 1,572,864 B -> 2,883,584
    u64* hbuf0       = (u64*)(ws + 2883584);         // 1,048,576 B
    u64* hbuf1       = (u64*)(ws + 3932160);         //   524,288 B
    float* h1f       = (float*)(ws + 4456448);       //   262,144 B
    _Float16* out0   = (_Float16*)(ws + 4718592);    // 134,217,728 B -> ~138.9 MB

    // poison tag buffers (0xFFFFFFFF != any step); replay-safe
    hipMemsetAsync(ws + 2883584, 0xFF, 1572864, stream);

    // L0: QW=32, NSUB=2, NQ=8, KT=10, dirs=2 -> 655360 elems
    hipLaunchKernelGGL(pack_w, dim3(2560), dim3(256), 0, stream,
                       Wih0, Whh0, W0pack, 64, 256, 10, 32, 2, 8, 655360);
    // L1: QW=16, NSUB=1, NQ=16, KT=24, dirs=1 -> 786432 elems
    hipLaunchKernelGGL(pack_w, dim3(3072), dim3(256), 0, stream,
                       Wih1, Whh1, W1pack, 512, 256, 24, 16, 1, 16, 786432);

    // L0 LDS: 81920(w) + 8448(h) + 2304(a) + 8448(g) = 101,120 -> 1 blk/CU
    hipFuncSetAttribute((const void*)(lstm_scan<2, 8, 32, true>),
                        hipFuncAttributeMaxDynamicSharedMemorySize, 101120);
    // L1 LDS: 98304(w) + 8448(h) + 16640(a) + 4352(g) = 127,744 -> 1 blk/CU
    hipFuncSetAttribute((const void*)(lstm_scan<16, 8, 16, false>),
                        hipFuncAttributeMaxDynamicSharedMemorySize, 127744);

    // L0: 32 groups (2 dir x 16 bg, M=16) x 8 col-blocks = 256 blocks
    hipLaunchKernelGGL((lstm_scan<2, 8, 32, true>), dim3(256), dim3(256), 101120, stream,
                       x, (const _Float16*)nullptr, W0pack, b0, hbuf0,
                       out0, (float*)nullptr);
    // L1 fwd: 16 groups (M=16) x 16 col-blocks = 256 blocks, K=768 folded
    hipLaunchKernelGGL((lstm_scan<16, 8, 16, false>), dim3(256), dim3(256), 127744, stream,
                       (const float*)nullptr, (const _Float16*)out0, W1pack, b1, hbuf1,
                       (_Float16*)nullptr, h1f);
    hipLaunchKernelGGL(tail_kernel, dim3(256), dim3(256), 0, stream,
                       out0, Wih1, b1, fcw, fcb, h1f, (float*)d_out);
}